// Round 1
// baseline (604.568 us; speedup 1.0000x reference)
//
#include <hip/hip_runtime.h>
#include <math.h>

typedef unsigned short u16;
typedef __bf16 bf16_t;
typedef u16 u16x4 __attribute__((ext_vector_type(4)));
typedef u16 u16x8 __attribute__((ext_vector_type(8)));
typedef bf16_t bf16x8 __attribute__((ext_vector_type(8)));
typedef float f32x4 __attribute__((ext_vector_type(4)));

__device__ __forceinline__ float bf2f(u16 v) {
    union { unsigned u; float f; } x; x.u = ((unsigned)v) << 16; return x.f;
}
__device__ __forceinline__ u16 f2bf(float f) {
    union { float f; unsigned u; } x; x.f = f;
    unsigned u = x.u;
    return (u16)((u + 0x7fffu + ((u >> 16) & 1u)) >> 16);
}

// ---------------------------------------------------------------------------
// Runtime dtype detector (probe = Wq). bf16: high byte of each u32 is sign/exp
// in [0x38,0x3F]; fp32: uniform mantissa byte. 64-lane majority => exact.
// ---------------------------------------------------------------------------
__device__ __forceinline__ bool is_bf16_input(const unsigned* __restrict__ probe) {
    unsigned w = probe[(threadIdx.x & 63) * 32771 + 7];
    unsigned b7 = (w >> 8) & 0x7f;
    bool hit = (b7 >= 0x38) && (b7 <= 0x3f);
    return __builtin_popcountll(__ballot(hit)) >= 32;
}

__global__ __launch_bounds__(256) void convert_kernel(
    const void* __restrict__ src, u16* __restrict__ dst, int n,
    const unsigned* __restrict__ probe)
{
    bool bf = is_bf16_input(probe);
    int i = (blockIdx.x * 256 + threadIdx.x) * 8;
    if (i >= n) return;
    if (bf) {
        *(u16x8*)&dst[i] = *(const u16x8*)&((const u16*)src)[i];
    } else {
        const float* s = (const float*)src + i;
        u16x8 o;
#pragma unroll
        for (int j = 0; j < 8; j++) o[j] = f2bf(s[j]);
        *(u16x8*)&dst[i] = o;
    }
}

__global__ __launch_bounds__(256) void tconv_kernel(
    const void* __restrict__ in, u16* __restrict__ out, int R, int C,
    const unsigned* __restrict__ probe)
{
    bool bf = is_bf16_input(probe);
    __shared__ u16 t[32][33];
    int x = threadIdx.x & 31, y = threadIdx.x >> 5;
    int bx = blockIdx.x * 32, by = blockIdx.y * 32;
    if (bf) {
        const u16* s = (const u16*)in;
#pragma unroll
        for (int i = 0; i < 32; i += 8)
            t[y + i][x] = s[(size_t)(by + y + i) * C + bx + x];
    } else {
        const float* s = (const float*)in;
#pragma unroll
        for (int i = 0; i < 32; i += 8)
            t[y + i][x] = f2bf(s[(size_t)(by + y + i) * C + bx + x]);
    }
    __syncthreads();
#pragma unroll
    for (int i = 0; i < 32; i += 8)
        out[(size_t)(bx + y + i) * R + by + x] = t[x][y + i];
}

__global__ __launch_bounds__(256) void transpose_kernel(
    const u16* __restrict__ in, u16* __restrict__ out, int R, int C)
{
    __shared__ u16 t[32][33];
    int x = threadIdx.x & 31, y = threadIdx.x >> 5;
    int bx = blockIdx.x * 32, by = blockIdx.y * 32;
#pragma unroll
    for (int i = 0; i < 32; i += 8)
        t[y + i][x] = in[(size_t)(by + y + i) * C + bx + x];
    __syncthreads();
#pragma unroll
    for (int i = 0; i < 32; i += 8)
        out[(size_t)(bx + y + i) * R + by + x] = t[x][y + i];
}

// ---------------------------------------------------------------------------
// GEMM: C[M,N] = A[M,K] @ BT[N,K]^T + bias[N]  (unchanged)
// ---------------------------------------------------------------------------
#define GSTR 40

__global__ __launch_bounds__(256) void gemm_bias_kernel(
    const u16* __restrict__ A, const u16* __restrict__ BT,
    const u16* __restrict__ bias, void* __restrict__ Cout,
    int M, int N, int K, const unsigned* __restrict__ probe)
{
    __shared__ __align__(16) u16 As[128 * GSTR];
    __shared__ __align__(16) u16 Bs[128 * GSTR];
    const int tid  = threadIdx.x;
    const int lane = tid & 63, wave = tid >> 6;
    const int quad = lane >> 4, li = lane & 15;
    const int bm = blockIdx.x * 128, bn = blockIdx.y * 128;
    const int wm = (wave >> 1) * 64, wn = (wave & 1) * 64;
    const int srow = tid >> 2;
    const int scol = (tid & 3) * 8;

    f32x4 acc[4][4] = {};

    for (int k0 = 0; k0 < K; k0 += 32) {
#pragma unroll
        for (int p = 0; p < 2; p++) {
            int r = srow + p * 64;
            u16x8 av = *(const u16x8*)&A [(size_t)(bm + r) * K + k0 + scol];
            u16x8 bv = *(const u16x8*)&BT[(size_t)(bn + r) * K + k0 + scol];
            *(u16x8*)&As[r * GSTR + scol] = av;
            *(u16x8*)&Bs[r * GSTR + scol] = bv;
        }
        __syncthreads();
        bf16x8 af[4], bfr[4];
#pragma unroll
        for (int i = 0; i < 4; i++)
            af[i]  = *(const bf16x8*)&As[(wm + i * 16 + li) * GSTR + quad * 8];
#pragma unroll
        for (int i = 0; i < 4; i++)
            bfr[i] = *(const bf16x8*)&Bs[(wn + i * 16 + li) * GSTR + quad * 8];
#pragma unroll
        for (int mt = 0; mt < 4; mt++)
#pragma unroll
            for (int nt = 0; nt < 4; nt++)
                acc[mt][nt] = __builtin_amdgcn_mfma_f32_16x16x32_bf16(
                    af[mt], bfr[nt], acc[mt][nt], 0, 0, 0);
        __syncthreads();
    }

    bool bf = probe ? is_bf16_input(probe) : true;
    if (bf) {
        u16* C16 = (u16*)Cout;
#pragma unroll
        for (int nt = 0; nt < 4; nt++) {
            int col = bn + wn + nt * 16 + li;
            float bb = bf2f(bias[col]);
#pragma unroll
            for (int mt = 0; mt < 4; mt++)
#pragma unroll
                for (int r = 0; r < 4; r++) {
                    int row = bm + wm + mt * 16 + quad * 4 + r;
                    C16[(size_t)row * N + col] = f2bf(acc[mt][nt][r] + bb);
                }
        }
    } else {
        float* Cf = (float*)Cout;
#pragma unroll
        for (int nt = 0; nt < 4; nt++) {
            int col = bn + wn + nt * 16 + li;
            float bb = bf2f(bias[col]);
#pragma unroll
            for (int mt = 0; mt < 4; mt++)
#pragma unroll
                for (int r = 0; r < 4; r++) {
                    int row = bm + wm + mt * 16 + quad * 4 + r;
                    Cf[(size_t)row * N + col] = acc[mt][nt][r] + bb;
                }
        }
    }
}

// ---------------------------------------------------------------------------
// Flash attention v4 (causal GQA) — single-wave blocks, no K/V staging.
//
// Rationale (rocprof v3): Occupancy 10.5% (≈0.85 waves/SIMD), MfmaUtil 8.4%,
// VALU 30.8%, HBM 3.9% — pure latency/imbalance bound. K+V for one (b,g) is
// only 1 MB (L2-resident), so LDS staging + the 2 barriers/tile it forces are
// overhead. New structure:
//   - 1 wave / block, 32 q-rows; grid (64, 16, 2) = 2048 blocks (8/CU avg).
//   - qt = 63 - blockIdx.x: longest (most-causal-work) blocks dispatch first.
//   - K,V fragments loaded directly from global (64B segments, L2/L3 hit).
//   - LDS = 2.5 KB (P relayout only); zero __syncthreads.
//   - Mask arithmetic only on the diagonal tile (kc == q0).
// Transposed score trick unchanged: S^T = K·Q^T, lane holds 4 contiguous keys
// of one q-row => 2-shuffle row reductions, b64 P stores.
// Q:[B*S, D]  K:[B*S, KV]  VT:[KV, B*S]  O:[B*S, D]. Grid (S/32, H, B).
// ---------------------------------------------------------------------------
__global__ __launch_bounds__(64) void flash_kernel(
    const u16* __restrict__ Q, const u16* __restrict__ Kg,
    const u16* __restrict__ VT, u16* __restrict__ O)
{
    constexpr int S = 2048, D = 2048, DH = 128, KVC = 512;
    constexpr float SCALE = 0.08838834764831845f;  // 1/sqrt(128)
    __shared__ __align__(16) u16 Pw[32 * 40];      // [qrow][key] 2560 B

    const int lane = threadIdx.x & 63;
    const int quad = lane >> 4, li = lane & 15;
    const int qt = 63 - (int)blockIdx.x;           // long blocks first
    const int h = blockIdx.y, b = blockIdx.z;
    const int g = h >> 2;
    const int q0 = qt * 32;                        // this wave's first q-row

    const u16* Qb = Q  + (size_t)b * S * D;
    const u16* Kb = Kg + (size_t)b * S * KVC + g * DH;   // [key][dh]
    const u16* Vg = VT + (size_t)g * DH * (2 * S) + (size_t)b * S; // [dh][key]

    // Q fragments: B-operand, rows q0 + m*16 + li, k = quad*8 (+c*32)
    bf16x8 qf[2][4];
#pragma unroll
    for (int m = 0; m < 2; m++)
#pragma unroll
        for (int c = 0; c < 4; c++)
            qf[m][c] = *(const bf16x8*)&Qb[(size_t)(q0 + m * 16 + li) * D
                                           + h * DH + c * 32 + quad * 8];

    f32x4 oacc[2][8] = {};
    float mr[2] = { -INFINITY, -INFINITY };
    float lr[2] = { 0.f, 0.f };

    for (int kc = 0; kc <= q0; kc += 32) {
        // S^T = K · Q^T : sacc[m][t], C row = key (quad*4+r), col = qrow (li)
        f32x4 sacc[2][2] = {};
#pragma unroll
        for (int c = 0; c < 4; c++) {
            bf16x8 kf0 = *(const bf16x8*)&Kb[(size_t)(kc + li) * KVC
                                             + c * 32 + quad * 8];
            bf16x8 kf1 = *(const bf16x8*)&Kb[(size_t)(kc + 16 + li) * KVC
                                             + c * 32 + quad * 8];
#pragma unroll
            for (int m = 0; m < 2; m++) {
                sacc[m][0] = __builtin_amdgcn_mfma_f32_16x16x32_bf16(
                    kf0, qf[m][c], sacc[m][0], 0, 0, 0);
                sacc[m][1] = __builtin_amdgcn_mfma_f32_16x16x32_bf16(
                    kf1, qf[m][c], sacc[m][1], 0, 0, 0);
            }
        }

        const bool diag = (kc == q0);   // only the diagonal tile needs masking
        float alpha_b[2][4];
#pragma unroll
        for (int m = 0; m < 2; m++) {
            f32x4 s0 = sacc[m][0] * SCALE;
            f32x4 s1 = sacc[m][1] * SCALE;
            if (diag) {
                int row = q0 + m * 16 + li;
#pragma unroll
                for (int r = 0; r < 4; r++) {
                    int k0 = kc + quad * 4 + r;
                    if (k0 > row)      s0[r] = -INFINITY;
                    if (k0 + 16 > row) s1[r] = -INFINITY;
                }
            }
            float mx = fmaxf(fmaxf(fmaxf(s0[0], s0[1]), fmaxf(s0[2], s0[3])),
                             fmaxf(fmaxf(s1[0], s1[1]), fmaxf(s1[2], s1[3])));
            mx = fmaxf(mx, __shfl_xor(mx, 16));
            mx = fmaxf(mx, __shfl_xor(mx, 32));
            float mnew = fmaxf(mr[m], mx);
            float al = __expf(mr[m] - mnew);
            mr[m] = mnew;
            f32x4 p0, p1;
            float ps = 0.f;
#pragma unroll
            for (int r = 0; r < 4; r++) {
                p0[r] = __expf(s0[r] - mnew);
                p1[r] = __expf(s1[r] - mnew);
                ps += p0[r] + p1[r];
            }
            ps += __shfl_xor(ps, 16);
            ps += __shfl_xor(ps, 32);
            lr[m] = lr[m] * al + ps;
            u16x4 c0, c1;
#pragma unroll
            for (int r = 0; r < 4; r++) { c0[r] = f2bf(p0[r]); c1[r] = f2bf(p1[r]); }
            *(u16x4*)&Pw[(m * 16 + li) * 40 + quad * 4]      = c0;
            *(u16x4*)&Pw[(m * 16 + li) * 40 + 16 + quad * 4] = c1;
#pragma unroll
            for (int r = 0; r < 4; r++)
                alpha_b[m][r] = __shfl(al, quad * 4 + r, 16);
        }

        // rescale O accumulators
#pragma unroll
        for (int m = 0; m < 2; m++)
#pragma unroll
            for (int dt = 0; dt < 8; dt++)
#pragma unroll
                for (int r = 0; r < 4; r++)
                    oacc[m][dt][r] *= alpha_b[m][r];

        // drain P stores (same wave) before vector re-read
        asm volatile("s_waitcnt lgkmcnt(0)" ::: "memory");
        union { u16x8 u; bf16x8 bv; } pc0, pc1;
        pc0.u = *(const u16x8*)&Pw[(0 * 16 + li) * 40 + quad * 8];
        pc1.u = *(const u16x8*)&Pw[(1 * 16 + li) * 40 + quad * 8];
        bf16x8 pf[2] = { pc0.bv, pc1.bv };

        // O += P · V   (V fragments direct from global, [dh][key] layout)
#pragma unroll
        for (int dt = 0; dt < 8; dt++) {
            bf16x8 vf = *(const bf16x8*)&Vg[(size_t)(dt * 16 + li) * (2 * S)
                                            + kc + quad * 8];
#pragma unroll
            for (int m = 0; m < 2; m++)
                oacc[m][dt] = __builtin_amdgcn_mfma_f32_16x16x32_bf16(
                    pf[m], vf, oacc[m][dt], 0, 0, 0);
        }
    }

    u16* Ob = O + (size_t)b * S * D;
#pragma unroll
    for (int m = 0; m < 2; m++) {
#pragma unroll
        for (int r = 0; r < 4; r++) {
            float linv = 1.0f / __shfl(lr[m], quad * 4 + r, 16);
            int row = q0 + m * 16 + quad * 4 + r;
#pragma unroll
            for (int dt = 0; dt < 8; dt++)
                Ob[(size_t)row * D + h * DH + dt * 16 + li] = f2bf(oacc[m][dt][r] * linv);
        }
    }
}

// ---------------------------------------------------------------------------
extern "C" void kernel_launch(void* const* d_in, const int* in_sizes, int n_in,
                              void* d_out, int out_size, void* d_ws, size_t ws_size,
                              hipStream_t stream)
{
    const void* X  = d_in[0];
    const void* Wq = d_in[3];
    const void* bq = d_in[4];
    const void* Wk = d_in[5];
    const void* bk = d_in[6];
    const void* Wv = d_in[7];
    const void* bv = d_in[8];
    const void* Wo = d_in[9];
    const void* bo = d_in[10];
    const unsigned* probe = (const unsigned*)d_in[3];

    u16* ws  = (u16*)d_ws;
    u16* Xc  = ws;                   // [4096][2048]
    u16* WT  = Xc  + 8388608;        // [2048][2048] WqT, later WoT
    u16* WkT = WT  + 4194304;        // [512][2048]
    u16* WvT = WkT + 1048576;        // [512][2048]
    u16* bqc = WvT + 1048576;        // 2048
    u16* bkc = bqc + 2048;           // 512
    u16* bvc = bkc + 512;            // 512
    u16* boc = bvc + 512;            // 2048
    u16* Qb  = boc + 2048;           // [4096][2048]
    u16* Kb  = Qb  + 8388608;        // [4096][512]
    u16* Vb  = Kb  + 2097152;        // [4096][512]
    u16* VTb = Vb  + 2097152;        // [512][4096]
    u16* Ob  = VTb + 2097152;        // [4096][2048]

    convert_kernel<<<4096, 256, 0, stream>>>(X,  Xc,  8388608, probe);
    convert_kernel<<<1,    256, 0, stream>>>(bq, bqc, 2048, probe);
    convert_kernel<<<1,    256, 0, stream>>>(bk, bkc, 512,  probe);
    convert_kernel<<<1,    256, 0, stream>>>(bv, bvc, 512,  probe);
    convert_kernel<<<1,    256, 0, stream>>>(bo, boc, 2048, probe);

    tconv_kernel<<<dim3(16, 64), 256, 0, stream>>>(Wk, WkT, 2048, 512, probe);
    tconv_kernel<<<dim3(16, 64), 256, 0, stream>>>(Wv, WvT, 2048, 512, probe);
    tconv_kernel<<<dim3(64, 64), 256, 0, stream>>>(Wq, WT,  2048, 2048, probe);

    gemm_bias_kernel<<<dim3(32, 16), 256, 0, stream>>>(Xc, WT,  bqc, Qb, 4096, 2048, 2048, nullptr);
    gemm_bias_kernel<<<dim3(32, 4),  256, 0, stream>>>(Xc, WkT, bkc, Kb, 4096, 512, 2048, nullptr);
    gemm_bias_kernel<<<dim3(32, 4),  256, 0, stream>>>(Xc, WvT, bvc, Vb, 4096, 512, 2048, nullptr);

    transpose_kernel<<<dim3(16, 128), 256, 0, stream>>>(Vb, VTb, 4096, 512);

    flash_kernel<<<dim3(64, 16, 2), 64, 0, stream>>>(Qb, Kb, VTb, Ob);

    tconv_kernel<<<dim3(64, 64), 256, 0, stream>>>(Wo, WT, 2048, 2048, probe);

    gemm_bias_kernel<<<dim3(32, 16), 256, 0, stream>>>(Ob, WT, boc, d_out, 4096, 2048, 2048, probe);
}

// Round 2
// 562.176 us; speedup vs baseline: 1.0754x; 1.0754x over previous
//
#include <hip/hip_runtime.h>
#include <math.h>

typedef unsigned short u16;
typedef __bf16 bf16_t;
typedef u16 u16x4 __attribute__((ext_vector_type(4)));
typedef u16 u16x8 __attribute__((ext_vector_type(8)));
typedef bf16_t bf16x8 __attribute__((ext_vector_type(8)));
typedef float f32x4 __attribute__((ext_vector_type(4)));

__device__ __forceinline__ float bf2f(u16 v) {
    union { unsigned u; float f; } x; x.u = ((unsigned)v) << 16; return x.f;
}
// Native f32->bf16 (RNE): compiler emits v_cvt_pk_bf16_f32 on gfx950,
// replacing the 4-op manual round-nearest-even bit sequence.
__device__ __forceinline__ u16 f2bf(float f) {
    union { bf16_t b; u16 u; } x; x.b = (bf16_t)f; return x.u;
}

// ---------------------------------------------------------------------------
// Runtime dtype detector (probe = Wq). bf16: high byte of each u32 is sign/exp
// in [0x38,0x3F]; fp32: uniform mantissa byte. 64-lane majority => exact.
// ---------------------------------------------------------------------------
__device__ __forceinline__ bool is_bf16_input(const unsigned* __restrict__ probe) {
    unsigned w = probe[(threadIdx.x & 63) * 32771 + 7];
    unsigned b7 = (w >> 8) & 0x7f;
    bool hit = (b7 >= 0x38) && (b7 <= 0x3f);
    return __builtin_popcountll(__ballot(hit)) >= 32;
}

__global__ __launch_bounds__(256) void convert_kernel(
    const void* __restrict__ src, u16* __restrict__ dst, int n,
    const unsigned* __restrict__ probe)
{
    bool bf = is_bf16_input(probe);
    int i = (blockIdx.x * 256 + threadIdx.x) * 8;
    if (i >= n) return;
    if (bf) {
        *(u16x8*)&dst[i] = *(const u16x8*)&((const u16*)src)[i];
    } else {
        const float* s = (const float*)src + i;
        u16x8 o;
#pragma unroll
        for (int j = 0; j < 8; j++) o[j] = f2bf(s[j]);
        *(u16x8*)&dst[i] = o;
    }
}

__global__ __launch_bounds__(256) void tconv_kernel(
    const void* __restrict__ in, u16* __restrict__ out, int R, int C,
    const unsigned* __restrict__ probe)
{
    bool bf = is_bf16_input(probe);
    __shared__ u16 t[32][33];
    int x = threadIdx.x & 31, y = threadIdx.x >> 5;
    int bx = blockIdx.x * 32, by = blockIdx.y * 32;
    if (bf) {
        const u16* s = (const u16*)in;
#pragma unroll
        for (int i = 0; i < 32; i += 8)
            t[y + i][x] = s[(size_t)(by + y + i) * C + bx + x];
    } else {
        const float* s = (const float*)in;
#pragma unroll
        for (int i = 0; i < 32; i += 8)
            t[y + i][x] = f2bf(s[(size_t)(by + y + i) * C + bx + x]);
    }
    __syncthreads();
#pragma unroll
    for (int i = 0; i < 32; i += 8)
        out[(size_t)(bx + y + i) * R + by + x] = t[x][y + i];
}

__global__ __launch_bounds__(256) void transpose_kernel(
    const u16* __restrict__ in, u16* __restrict__ out, int R, int C)
{
    __shared__ u16 t[32][33];
    int x = threadIdx.x & 31, y = threadIdx.x >> 5;
    int bx = blockIdx.x * 32, by = blockIdx.y * 32;
#pragma unroll
    for (int i = 0; i < 32; i += 8)
        t[y + i][x] = in[(size_t)(by + y + i) * C + bx + x];
    __syncthreads();
#pragma unroll
    for (int i = 0; i < 32; i += 8)
        out[(size_t)(bx + y + i) * R + by + x] = t[x][y + i];
}

// ---------------------------------------------------------------------------
// GEMM: C[M,N] = (A[M,K] @ BT[N,K]^T + bias[N]) * scale
// scale lets us fold attention's 1/sqrt(dh) into the Q projection for free.
// ---------------------------------------------------------------------------
#define GSTR 40

__global__ __launch_bounds__(256) void gemm_bias_kernel(
    const u16* __restrict__ A, const u16* __restrict__ BT,
    const u16* __restrict__ bias, void* __restrict__ Cout,
    int M, int N, int K, const unsigned* __restrict__ probe, float scale)
{
    __shared__ __align__(16) u16 As[128 * GSTR];
    __shared__ __align__(16) u16 Bs[128 * GSTR];
    const int tid  = threadIdx.x;
    const int lane = tid & 63, wave = tid >> 6;
    const int quad = lane >> 4, li = lane & 15;
    const int bm = blockIdx.x * 128, bn = blockIdx.y * 128;
    const int wm = (wave >> 1) * 64, wn = (wave & 1) * 64;
    const int srow = tid >> 2;
    const int scol = (tid & 3) * 8;

    f32x4 acc[4][4] = {};

    for (int k0 = 0; k0 < K; k0 += 32) {
#pragma unroll
        for (int p = 0; p < 2; p++) {
            int r = srow + p * 64;
            u16x8 av = *(const u16x8*)&A [(size_t)(bm + r) * K + k0 + scol];
            u16x8 bv = *(const u16x8*)&BT[(size_t)(bn + r) * K + k0 + scol];
            *(u16x8*)&As[r * GSTR + scol] = av;
            *(u16x8*)&Bs[r * GSTR + scol] = bv;
        }
        __syncthreads();
        bf16x8 af[4], bfr[4];
#pragma unroll
        for (int i = 0; i < 4; i++)
            af[i]  = *(const bf16x8*)&As[(wm + i * 16 + li) * GSTR + quad * 8];
#pragma unroll
        for (int i = 0; i < 4; i++)
            bfr[i] = *(const bf16x8*)&Bs[(wn + i * 16 + li) * GSTR + quad * 8];
#pragma unroll
        for (int mt = 0; mt < 4; mt++)
#pragma unroll
            for (int nt = 0; nt < 4; nt++)
                acc[mt][nt] = __builtin_amdgcn_mfma_f32_16x16x32_bf16(
                    af[mt], bfr[nt], acc[mt][nt], 0, 0, 0);
        __syncthreads();
    }

    bool bf = probe ? is_bf16_input(probe) : true;
    if (bf) {
        u16* C16 = (u16*)Cout;
#pragma unroll
        for (int nt = 0; nt < 4; nt++) {
            int col = bn + wn + nt * 16 + li;
            float bb = bf2f(bias[col]);
#pragma unroll
            for (int mt = 0; mt < 4; mt++)
#pragma unroll
                for (int r = 0; r < 4; r++) {
                    int row = bm + wm + mt * 16 + quad * 4 + r;
                    C16[(size_t)row * N + col] = f2bf((acc[mt][nt][r] + bb) * scale);
                }
        }
    } else {
        float* Cf = (float*)Cout;
#pragma unroll
        for (int nt = 0; nt < 4; nt++) {
            int col = bn + wn + nt * 16 + li;
            float bb = bf2f(bias[col]);
#pragma unroll
            for (int mt = 0; mt < 4; mt++)
#pragma unroll
                for (int r = 0; r < 4; r++) {
                    int row = bm + wm + mt * 16 + quad * 4 + r;
                    Cf[(size_t)row * N + col] = (acc[mt][nt][r] + bb) * scale;
                }
        }
    }
}

// ---------------------------------------------------------------------------
// Flash attention v5 (causal GQA). Back to the proven v3 skeleton:
// 4 waves/block, 128 q-rows, K/V LDS staging + register prefetch (that
// structure was the latency-hiding; removing it in v4 cost +76 µs).
// VALU-cut changes on top (softmax VALU was ~3x the MFMA cycles):
//   - diag-only causal masking (only the kc==q0w tile can clamp)
//   - 1/sqrt(dh) pre-folded into Q (GEMM epilogue scale)
//   - native bf16 converts (v_cvt_pk_bf16_f32) instead of 4-op manual RNE
//   - T13 defer-max (THR=5): skip O-rescale + alpha shuffles unless the
//     tile max exceeds the running max by >5; P bounded by e^5, bf16-safe.
// Q:[B*S, D] (pre-scaled)  K:[B*S, KV]  VT:[KV, B*S]  O:[B*S, D].
// Grid (S/128, H, B).
// ---------------------------------------------------------------------------
__global__ __launch_bounds__(256) void flash_kernel(
    const u16* __restrict__ Q, const u16* __restrict__ Kg,
    const u16* __restrict__ VT, u16* __restrict__ O)
{
    constexpr int S = 2048, D = 2048, DH = 128, KVC = 512;
    constexpr float THR = 5.0f;
    __shared__ __align__(16) u16 Ks[32 * 136];   // [key][dh]   8704 B
    __shared__ __align__(16) u16 Vt[128 * 40];   // [dh][key]  10240 B
    __shared__ __align__(16) u16 Pw[4][32 * 40]; // [qrow][key] 10240 B

    const int tid  = threadIdx.x;
    const int wave = tid >> 6, lane = tid & 63;
    const int quad = lane >> 4, li = lane & 15;
    const int qt = blockIdx.x, h = blockIdx.y, b = blockIdx.z;
    const int g = h >> 2;
    const int q0w = qt * 128 + wave * 32;        // this wave's first q-row

    const u16* Qb = Q  + (size_t)b * S * D;
    const u16* Kb = Kg + (size_t)b * S * KVC;
    const u16* Vg = VT + (size_t)g * DH * (2 * S) + (size_t)b * S;

    // Q fragments: B-operand, rows q0w + m*16 + li, k = quad*8 (+c*32)
    bf16x8 qf[2][4];
#pragma unroll
    for (int m = 0; m < 2; m++)
#pragma unroll
        for (int c = 0; c < 4; c++)
            qf[m][c] = *(const bf16x8*)&Qb[(size_t)(q0w + m * 16 + li) * D
                                           + h * DH + c * 32 + quad * 8];

    f32x4 oacc[2][8] = {};
    float mr[2] = { -INFINITY, -INFINITY };
    float lr[2] = { 0.f, 0.f };

    const int kend = qt * 128 + 128;

    // --- register prefetch of tile kc=0 ---
    u16x8 kreg[2], vreg[2];
#pragma unroll
    for (int ch = 0; ch < 2; ch++) {
        int idx = tid + ch * 256;
        kreg[ch] = *(const u16x8*)&Kb[(size_t)(idx >> 4) * KVC + g * DH + (idx & 15) * 8];
        vreg[ch] = *(const u16x8*)&Vg[(size_t)(idx >> 2) * (2 * S) + (idx & 3) * 8];
    }

    for (int kc = 0; kc < kend; kc += 32) {
        // commit prefetched tile to LDS
#pragma unroll
        for (int ch = 0; ch < 2; ch++) {
            int idx = tid + ch * 256;
            *(u16x8*)&Ks[(idx >> 4) * 136 + (idx & 15) * 8] = kreg[ch];
            *(u16x8*)&Vt[(idx >> 2) * 40  + (idx & 3) * 8]  = vreg[ch];
        }
        __syncthreads();

        // issue prefetch for next tile (overlaps with compute below)
        int kn = kc + 32;
        if (kn < kend) {
#pragma unroll
            for (int ch = 0; ch < 2; ch++) {
                int idx = tid + ch * 256;
                kreg[ch] = *(const u16x8*)&Kb[(size_t)(kn + (idx >> 4)) * KVC
                                              + g * DH + (idx & 15) * 8];
                vreg[ch] = *(const u16x8*)&Vg[(size_t)(idx >> 2) * (2 * S)
                                              + kn + (idx & 3) * 8];
            }
        }

        if (kc <= q0w) {   // causal: tiles with kc > q0w are fully masked
            // S^T = K · Q^T : sacc[m][t], C row = key (quad*4+r), col = qrow (li)
            f32x4 sacc[2][2] = {};
#pragma unroll
            for (int t = 0; t < 2; t++)
#pragma unroll
                for (int c = 0; c < 4; c++) {
                    bf16x8 kf = *(const bf16x8*)&Ks[(t * 16 + li) * 136 + c * 32 + quad * 8];
#pragma unroll
                    for (int m = 0; m < 2; m++)
                        sacc[m][t] = __builtin_amdgcn_mfma_f32_16x16x32_bf16(
                            kf, qf[m][c], sacc[m][t], 0, 0, 0);
                }

            const bool diag = (kc == q0w);  // kc < q0w => max key kc+31 < q0w <= row
#pragma unroll
            for (int m = 0; m < 2; m++) {
                f32x4 s0 = sacc[m][0];
                f32x4 s1 = sacc[m][1];
                if (diag) {
                    int row = q0w + m * 16 + li;
#pragma unroll
                    for (int r = 0; r < 4; r++) {
                        int k0 = kc + quad * 4 + r;
                        if (k0 > row)      s0[r] = -INFINITY;
                        if (k0 + 16 > row) s1[r] = -INFINITY;
                    }
                }
                float mx = fmaxf(fmaxf(fmaxf(s0[0], s0[1]), fmaxf(s0[2], s0[3])),
                                 fmaxf(fmaxf(s1[0], s1[1]), fmaxf(s1[2], s1[3])));
                mx = fmaxf(mx, __shfl_xor(mx, 16));
                mx = fmaxf(mx, __shfl_xor(mx, 32));
                // defer-max: only pay rescale when the max actually grows
                if (__any(mx > mr[m] + THR)) {
                    float mnew = fmaxf(mr[m], mx);
                    float al = __expf(mr[m] - mnew);
                    mr[m] = mnew;
                    lr[m] *= al;
                    float alr[4];
#pragma unroll
                    for (int r = 0; r < 4; r++)
                        alr[r] = __shfl(al, quad * 4 + r, 16);
#pragma unroll
                    for (int dt = 0; dt < 8; dt++)
#pragma unroll
                        for (int r = 0; r < 4; r++)
                            oacc[m][dt][r] *= alr[r];
                }
                const float mref = mr[m];
                f32x4 p0, p1;
                float ps = 0.f;
#pragma unroll
                for (int r = 0; r < 4; r++) {
                    p0[r] = __expf(s0[r] - mref);
                    p1[r] = __expf(s1[r] - mref);
                    ps += p0[r] + p1[r];
                }
                ps += __shfl_xor(ps, 16);
                ps += __shfl_xor(ps, 32);
                lr[m] += ps;
                u16x4 c0, c1;
#pragma unroll
                for (int r = 0; r < 4; r++) { c0[r] = f2bf(p0[r]); c1[r] = f2bf(p1[r]); }
                *(u16x4*)&Pw[wave][(m * 16 + li) * 40 + quad * 4]      = c0;
                *(u16x4*)&Pw[wave][(m * 16 + li) * 40 + 16 + quad * 4] = c1;
            }

            // drain P stores (same wave) before vector re-read
            asm volatile("s_waitcnt lgkmcnt(0)" ::: "memory");
            union { u16x8 u; bf16x8 bv; } pc0, pc1;
            pc0.u = *(const u16x8*)&Pw[wave][(0 * 16 + li) * 40 + quad * 8];
            pc1.u = *(const u16x8*)&Pw[wave][(1 * 16 + li) * 40 + quad * 8];
            bf16x8 pf[2] = { pc0.bv, pc1.bv };

            // O += P · V
#pragma unroll
            for (int dt = 0; dt < 8; dt++) {
                bf16x8 vf = *(const bf16x8*)&Vt[(dt * 16 + li) * 40 + quad * 8];
#pragma unroll
                for (int m = 0; m < 2; m++)
                    oacc[m][dt] = __builtin_amdgcn_mfma_f32_16x16x32_bf16(
                        pf[m], vf, oacc[m][dt], 0, 0, 0);
            }
        }
        __syncthreads();
    }

    u16* Ob = O + (size_t)b * S * D;
#pragma unroll
    for (int m = 0; m < 2; m++) {
#pragma unroll
        for (int r = 0; r < 4; r++) {
            float linv = 1.0f / __shfl(lr[m], quad * 4 + r, 16);
            int row = q0w + m * 16 + quad * 4 + r;
#pragma unroll
            for (int dt = 0; dt < 8; dt++)
                Ob[(size_t)row * D + h * DH + dt * 16 + li] = f2bf(oacc[m][dt][r] * linv);
        }
    }
}

// ---------------------------------------------------------------------------
extern "C" void kernel_launch(void* const* d_in, const int* in_sizes, int n_in,
                              void* d_out, int out_size, void* d_ws, size_t ws_size,
                              hipStream_t stream)
{
    const void* X  = d_in[0];
    const void* Wq = d_in[3];
    const void* bq = d_in[4];
    const void* Wk = d_in[5];
    const void* bk = d_in[6];
    const void* Wv = d_in[7];
    const void* bv = d_in[8];
    const void* Wo = d_in[9];
    const void* bo = d_in[10];
    const unsigned* probe = (const unsigned*)d_in[3];

    u16* ws  = (u16*)d_ws;
    u16* Xc  = ws;                   // [4096][2048]
    u16* WT  = Xc  + 8388608;        // [2048][2048] WqT, later WoT
    u16* WkT = WT  + 4194304;        // [512][2048]
    u16* WvT = WkT + 1048576;        // [512][2048]
    u16* bqc = WvT + 1048576;        // 2048
    u16* bkc = bqc + 2048;           // 512
    u16* bvc = bkc + 512;            // 512
    u16* boc = bvc + 512;            // 2048
    u16* Qb  = boc + 2048;           // [4096][2048]
    u16* Kb  = Qb  + 8388608;        // [4096][512]
    u16* Vb  = Kb  + 2097152;        // [4096][512]
    u16* VTb = Vb  + 2097152;        // [512][4096]
    u16* Ob  = VTb + 2097152;        // [4096][2048]

    convert_kernel<<<4096, 256, 0, stream>>>(X,  Xc,  8388608, probe);
    convert_kernel<<<1,    256, 0, stream>>>(bq, bqc, 2048, probe);
    convert_kernel<<<1,    256, 0, stream>>>(bk, bkc, 512,  probe);
    convert_kernel<<<1,    256, 0, stream>>>(bv, bvc, 512,  probe);
    convert_kernel<<<1,    256, 0, stream>>>(bo, boc, 2048, probe);

    tconv_kernel<<<dim3(16, 64), 256, 0, stream>>>(Wk, WkT, 2048, 512, probe);
    tconv_kernel<<<dim3(16, 64), 256, 0, stream>>>(Wv, WvT, 2048, 512, probe);
    tconv_kernel<<<dim3(64, 64), 256, 0, stream>>>(Wq, WT,  2048, 2048, probe);

    // 1/sqrt(DH) folded into Q projection (scale epilogue)
    gemm_bias_kernel<<<dim3(32, 16), 256, 0, stream>>>(Xc, WT,  bqc, Qb, 4096, 2048, 2048, nullptr, 0.08838834764831845f);
    gemm_bias_kernel<<<dim3(32, 4),  256, 0, stream>>>(Xc, WkT, bkc, Kb, 4096, 512, 2048, nullptr, 1.0f);
    gemm_bias_kernel<<<dim3(32, 4),  256, 0, stream>>>(Xc, WvT, bvc, Vb, 4096, 512, 2048, nullptr, 1.0f);

    transpose_kernel<<<dim3(16, 128), 256, 0, stream>>>(Vb, VTb, 4096, 512);

    flash_kernel<<<dim3(16, 16, 2), 256, 0, stream>>>(Qb, Kb, VTb, Ob);

    tconv_kernel<<<dim3(64, 64), 256, 0, stream>>>(Wo, WT, 2048, 2048, probe);

    gemm_bias_kernel<<<dim3(32, 16), 256, 0, stream>>>(Ob, WT, boc, d_out, 4096, 2048, 2048, probe, 1.0f);
}

// Round 3
// 545.297 us; speedup vs baseline: 1.1087x; 1.0310x over previous
//
#include <hip/hip_runtime.h>
#include <math.h>

typedef unsigned short u16;
typedef __bf16 bf16_t;
typedef u16 u16x4 __attribute__((ext_vector_type(4)));
typedef u16 u16x8 __attribute__((ext_vector_type(8)));
typedef bf16_t bf16x8 __attribute__((ext_vector_type(8)));
typedef float f32x4 __attribute__((ext_vector_type(4)));

__device__ __forceinline__ float bf2f(u16 v) {
    union { unsigned u; float f; } x; x.u = ((unsigned)v) << 16; return x.f;
}
// Native f32->bf16 (RNE): compiler emits v_cvt_pk_bf16_f32 on gfx950.
__device__ __forceinline__ u16 f2bf(float f) {
    union { bf16_t b; u16 u; } x; x.b = (bf16_t)f; return x.u;
}

// ---------------------------------------------------------------------------
// Runtime dtype detector (probe = Wq). bf16: high byte of each u32 is sign/exp
// in [0x38,0x3F]; fp32: uniform mantissa byte. 64-lane majority => exact.
// ---------------------------------------------------------------------------
__device__ __forceinline__ bool is_bf16_input(const unsigned* __restrict__ probe) {
    unsigned w = probe[(threadIdx.x & 63) * 32771 + 7];
    unsigned b7 = (w >> 8) & 0x7f;
    bool hit = (b7 >= 0x38) && (b7 <= 0x3f);
    return __builtin_popcountll(__ballot(hit)) >= 32;
}

__global__ __launch_bounds__(256) void convert_kernel(
    const void* __restrict__ src, u16* __restrict__ dst, int n,
    const unsigned* __restrict__ probe)
{
    bool bf = is_bf16_input(probe);
    int i = (blockIdx.x * 256 + threadIdx.x) * 8;
    if (i >= n) return;
    if (bf) {
        *(u16x8*)&dst[i] = *(const u16x8*)&((const u16*)src)[i];
    } else {
        const float* s = (const float*)src + i;
        u16x8 o;
#pragma unroll
        for (int j = 0; j < 8; j++) o[j] = f2bf(s[j]);
        *(u16x8*)&dst[i] = o;
    }
}

__global__ __launch_bounds__(256) void tconv_kernel(
    const void* __restrict__ in, u16* __restrict__ out, int R, int C,
    const unsigned* __restrict__ probe)
{
    bool bf = is_bf16_input(probe);
    __shared__ u16 t[32][33];
    int x = threadIdx.x & 31, y = threadIdx.x >> 5;
    int bx = blockIdx.x * 32, by = blockIdx.y * 32;
    if (bf) {
        const u16* s = (const u16*)in;
#pragma unroll
        for (int i = 0; i < 32; i += 8)
            t[y + i][x] = s[(size_t)(by + y + i) * C + bx + x];
    } else {
        const float* s = (const float*)in;
#pragma unroll
        for (int i = 0; i < 32; i += 8)
            t[y + i][x] = f2bf(s[(size_t)(by + y + i) * C + bx + x]);
    }
    __syncthreads();
#pragma unroll
    for (int i = 0; i < 32; i += 8)
        out[(size_t)(bx + y + i) * R + by + x] = t[x][y + i];
}

__global__ __launch_bounds__(256) void transpose_kernel(
    const u16* __restrict__ in, u16* __restrict__ out, int R, int C)
{
    __shared__ u16 t[32][33];
    int x = threadIdx.x & 31, y = threadIdx.x >> 5;
    int bx = blockIdx.x * 32, by = blockIdx.y * 32;
#pragma unroll
    for (int i = 0; i < 32; i += 8)
        t[y + i][x] = in[(size_t)(by + y + i) * C + bx + x];
    __syncthreads();
#pragma unroll
    for (int i = 0; i < 32; i += 8)
        out[(size_t)(bx + y + i) * R + by + x] = t[x][y + i];
}

// ---------------------------------------------------------------------------
// GEMM: C[M,N] = (A[M,K] @ BT[N,K]^T + bias[N]) * scale
// ---------------------------------------------------------------------------
#define GSTR 40

__global__ __launch_bounds__(256) void gemm_bias_kernel(
    const u16* __restrict__ A, const u16* __restrict__ BT,
    const u16* __restrict__ bias, void* __restrict__ Cout,
    int M, int N, int K, const unsigned* __restrict__ probe, float scale)
{
    __shared__ __align__(16) u16 As[128 * GSTR];
    __shared__ __align__(16) u16 Bs[128 * GSTR];
    const int tid  = threadIdx.x;
    const int lane = tid & 63, wave = tid >> 6;
    const int quad = lane >> 4, li = lane & 15;
    const int bm = blockIdx.x * 128, bn = blockIdx.y * 128;
    const int wm = (wave >> 1) * 64, wn = (wave & 1) * 64;
    const int srow = tid >> 2;
    const int scol = (tid & 3) * 8;

    f32x4 acc[4][4] = {};

    for (int k0 = 0; k0 < K; k0 += 32) {
#pragma unroll
        for (int p = 0; p < 2; p++) {
            int r = srow + p * 64;
            u16x8 av = *(const u16x8*)&A [(size_t)(bm + r) * K + k0 + scol];
            u16x8 bv = *(const u16x8*)&BT[(size_t)(bn + r) * K + k0 + scol];
            *(u16x8*)&As[r * GSTR + scol] = av;
            *(u16x8*)&Bs[r * GSTR + scol] = bv;
        }
        __syncthreads();
        bf16x8 af[4], bfr[4];
#pragma unroll
        for (int i = 0; i < 4; i++)
            af[i]  = *(const bf16x8*)&As[(wm + i * 16 + li) * GSTR + quad * 8];
#pragma unroll
        for (int i = 0; i < 4; i++)
            bfr[i] = *(const bf16x8*)&Bs[(wn + i * 16 + li) * GSTR + quad * 8];
#pragma unroll
        for (int mt = 0; mt < 4; mt++)
#pragma unroll
            for (int nt = 0; nt < 4; nt++)
                acc[mt][nt] = __builtin_amdgcn_mfma_f32_16x16x32_bf16(
                    af[mt], bfr[nt], acc[mt][nt], 0, 0, 0);
        __syncthreads();
    }

    bool bf = probe ? is_bf16_input(probe) : true;
    if (bf) {
        u16* C16 = (u16*)Cout;
#pragma unroll
        for (int nt = 0; nt < 4; nt++) {
            int col = bn + wn + nt * 16 + li;
            float bb = bf2f(bias[col]);
#pragma unroll
            for (int mt = 0; mt < 4; mt++)
#pragma unroll
                for (int r = 0; r < 4; r++) {
                    int row = bm + wm + mt * 16 + quad * 4 + r;
                    C16[(size_t)row * N + col] = f2bf((acc[mt][nt][r] + bb) * scale);
                }
        }
    } else {
        float* Cf = (float*)Cout;
#pragma unroll
        for (int nt = 0; nt < 4; nt++) {
            int col = bn + wn + nt * 16 + li;
            float bb = bf2f(bias[col]);
#pragma unroll
            for (int mt = 0; mt < 4; mt++)
#pragma unroll
                for (int r = 0; r < 4; r++) {
                    int row = bm + wm + mt * 16 + quad * 4 + r;
                    Cf[(size_t)row * N + col] = (acc[mt][nt][r] + bb) * scale;
                }
        }
    }
}

// ---------------------------------------------------------------------------
// Flash attention v6 (causal GQA). v3 skeleton (4 waves/block, 128 q-rows,
// LDS staging + register prefetch, straight-line softmax) with KVBLK=64:
// the per-iteration fixed latency (2 barriers, ~16 DS-shuffles, P LDS
// round-trip) measured ~4900 cy/iter dominates the MFMA (~155cy) and VALU
// (~500cy) issued per iter; doubling the key tile halves the iteration count
// of every block (heavy diagonal block 64 -> 32 iters), amortizing those
// fixed costs over 2x keys. Defer-max branch from v5 removed (it broke the
// compiler's loop pipelining: dur 165->206 with LESS VALU work).
// exp2 variant: Q pre-scaled by log2(e)/sqrt(dh) -> exp2f = bare v_exp_f32.
// Q:[B*S, D] (pre-scaled)  K:[B*S, KV]  VT:[KV, B*S]  O:[B*S, D].
// Grid (S/128, H, B).
// ---------------------------------------------------------------------------
__global__ __launch_bounds__(256) void flash_kernel(
    const u16* __restrict__ Q, const u16* __restrict__ Kg,
    const u16* __restrict__ VT, u16* __restrict__ O)
{
    constexpr int S = 2048, D = 2048, DH = 128, KVC = 512;
    __shared__ __align__(16) u16 Ks[64 * 136];   // [key][dh]   17408 B
    __shared__ __align__(16) u16 Vt[128 * 72];   // [dh][key]   18432 B
    __shared__ __align__(16) u16 Pw[4][32 * 72]; // [qrow][key] 18432 B

    const int tid  = threadIdx.x;
    const int wave = tid >> 6, lane = tid & 63;
    const int quad = lane >> 4, li = lane & 15;
    const int qt = blockIdx.x, h = blockIdx.y, b = blockIdx.z;
    const int g = h >> 2;
    const int q0w = qt * 128 + wave * 32;        // this wave's first q-row

    const u16* Qb = Q  + (size_t)b * S * D;
    const u16* Kb = Kg + (size_t)b * S * KVC;
    const u16* Vg = VT + (size_t)g * DH * (2 * S) + (size_t)b * S;

    // Q fragments: B-operand, rows q0w + m*16 + li, k = quad*8 (+c*32)
    bf16x8 qf[2][4];
#pragma unroll
    for (int m = 0; m < 2; m++)
#pragma unroll
        for (int c = 0; c < 4; c++)
            qf[m][c] = *(const bf16x8*)&Qb[(size_t)(q0w + m * 16 + li) * D
                                           + h * DH + c * 32 + quad * 8];

    f32x4 oacc[2][8] = {};
    float mr[2] = { -INFINITY, -INFINITY };
    float lr[2] = { 0.f, 0.f };

    const int kend = qt * 128 + 128;

    // --- register prefetch of tile kc=0 (64 keys) ---
    u16x8 kreg[4], vreg[4];
#pragma unroll
    for (int ch = 0; ch < 4; ch++) {
        int idx = tid + ch * 256;
        kreg[ch] = *(const u16x8*)&Kb[(size_t)(idx >> 4) * KVC + g * DH + (idx & 15) * 8];
        vreg[ch] = *(const u16x8*)&Vg[(size_t)(idx >> 3) * (2 * S) + (idx & 7) * 8];
    }

    for (int kc = 0; kc < kend; kc += 64) {
        // commit prefetched tile to LDS
#pragma unroll
        for (int ch = 0; ch < 4; ch++) {
            int idx = tid + ch * 256;
            *(u16x8*)&Ks[(idx >> 4) * 136 + (idx & 15) * 8] = kreg[ch];
            *(u16x8*)&Vt[(idx >> 3) * 72  + (idx & 7) * 8]  = vreg[ch];
        }
        __syncthreads();

        // issue prefetch for next tile (overlaps with compute below)
        int kn = kc + 64;
        if (kn < kend) {
#pragma unroll
            for (int ch = 0; ch < 4; ch++) {
                int idx = tid + ch * 256;
                kreg[ch] = *(const u16x8*)&Kb[(size_t)(kn + (idx >> 4)) * KVC
                                              + g * DH + (idx & 15) * 8];
                vreg[ch] = *(const u16x8*)&Vg[(size_t)(idx >> 3) * (2 * S)
                                              + kn + (idx & 7) * 8];
            }
        }

        if (kc <= q0w) {   // causal: tiles fully above the diagonal are skipped
            // S^T = K · Q^T : sacc[m][t], C row = key (quad*4+r), col = qrow (li)
            f32x4 sacc[2][4] = {};
#pragma unroll
            for (int t = 0; t < 4; t++)
#pragma unroll
                for (int c = 0; c < 4; c++) {
                    bf16x8 kf = *(const bf16x8*)&Ks[(t * 16 + li) * 136 + c * 32 + quad * 8];
#pragma unroll
                    for (int m = 0; m < 2; m++)
                        sacc[m][t] = __builtin_amdgcn_mfma_f32_16x16x32_bf16(
                            kf, qf[m][c], sacc[m][t], 0, 0, 0);
                }

            const bool diag = (kc + 64 > q0w);   // only the diagonal tile masks
            float alpha_b[2][4];
#pragma unroll
            for (int m = 0; m < 2; m++) {
                f32x4 s0 = sacc[m][0], s1 = sacc[m][1];
                f32x4 s2 = sacc[m][2], s3 = sacc[m][3];
                if (diag) {
                    int row = q0w + m * 16 + li;
#pragma unroll
                    for (int r = 0; r < 4; r++) {
                        int k0 = kc + quad * 4 + r;
                        if (k0 > row)      s0[r] = -INFINITY;
                        if (k0 + 16 > row) s1[r] = -INFINITY;
                        if (k0 + 32 > row) s2[r] = -INFINITY;
                        if (k0 + 48 > row) s3[r] = -INFINITY;
                    }
                }
                f32x4 sm01 = fmaxf(s0[0], s1[0]), dummy; (void)dummy;
                float mx;
                {
                    f32x4 a, bmx;
#pragma unroll
                    for (int r = 0; r < 4; r++) a[r] = fmaxf(fmaxf(s0[r], s1[r]),
                                                             fmaxf(s2[r], s3[r]));
                    (void)bmx; (void)sm01;
                    mx = fmaxf(fmaxf(a[0], a[1]), fmaxf(a[2], a[3]));
                }
                mx = fmaxf(mx, __shfl_xor(mx, 16));
                mx = fmaxf(mx, __shfl_xor(mx, 32));
                float mnew = fmaxf(mr[m], mx);
                float al = exp2f(mr[m] - mnew);
                mr[m] = mnew;
                f32x4 p0, p1, p2, p3;
                float ps = 0.f;
#pragma unroll
                for (int r = 0; r < 4; r++) {
                    p0[r] = exp2f(s0[r] - mnew);
                    p1[r] = exp2f(s1[r] - mnew);
                    p2[r] = exp2f(s2[r] - mnew);
                    p3[r] = exp2f(s3[r] - mnew);
                    ps += (p0[r] + p1[r]) + (p2[r] + p3[r]);
                }
                ps += __shfl_xor(ps, 16);
                ps += __shfl_xor(ps, 32);
                lr[m] = lr[m] * al + ps;
                u16x4 c0, c1, c2, c3;
#pragma unroll
                for (int r = 0; r < 4; r++) {
                    c0[r] = f2bf(p0[r]); c1[r] = f2bf(p1[r]);
                    c2[r] = f2bf(p2[r]); c3[r] = f2bf(p3[r]);
                }
                *(u16x4*)&Pw[wave][(m * 16 + li) * 72 + quad * 4]      = c0;
                *(u16x4*)&Pw[wave][(m * 16 + li) * 72 + 16 + quad * 4] = c1;
                *(u16x4*)&Pw[wave][(m * 16 + li) * 72 + 32 + quad * 4] = c2;
                *(u16x4*)&Pw[wave][(m * 16 + li) * 72 + 48 + quad * 4] = c3;
#pragma unroll
                for (int r = 0; r < 4; r++)
                    alpha_b[m][r] = __shfl(al, quad * 4 + r, 16);
            }

            // rescale O accumulators
#pragma unroll
            for (int m = 0; m < 2; m++)
#pragma unroll
                for (int dt = 0; dt < 8; dt++)
#pragma unroll
                    for (int r = 0; r < 4; r++)
                        oacc[m][dt][r] *= alpha_b[m][r];

            // drain P stores (same wave) before vector re-read
            asm volatile("s_waitcnt lgkmcnt(0)" ::: "memory");
            union { u16x8 u; bf16x8 bv; } pc;
            bf16x8 pf[2][2];
#pragma unroll
            for (int m = 0; m < 2; m++)
#pragma unroll
                for (int ks = 0; ks < 2; ks++) {
                    pc.u = *(const u16x8*)&Pw[wave][(m * 16 + li) * 72
                                                    + ks * 32 + quad * 8];
                    pf[m][ks] = pc.bv;
                }

            // O += P · V  (two 32-key chunks)
#pragma unroll
            for (int dt = 0; dt < 8; dt++) {
#pragma unroll
                for (int ks = 0; ks < 2; ks++) {
                    bf16x8 vf = *(const bf16x8*)&Vt[(dt * 16 + li) * 72
                                                    + ks * 32 + quad * 8];
#pragma unroll
                    for (int m = 0; m < 2; m++)
                        oacc[m][dt] = __builtin_amdgcn_mfma_f32_16x16x32_bf16(
                            pf[m][ks], vf, oacc[m][dt], 0, 0, 0);
                }
            }
        }
        __syncthreads();
    }

    u16* Ob = O + (size_t)b * S * D;
#pragma unroll
    for (int m = 0; m < 2; m++) {
#pragma unroll
        for (int r = 0; r < 4; r++) {
            float linv = 1.0f / __shfl(lr[m], quad * 4 + r, 16);
            int row = q0w + m * 16 + quad * 4 + r;
#pragma unroll
            for (int dt = 0; dt < 8; dt++)
                Ob[(size_t)row * D + h * DH + dt * 16 + li] = f2bf(oacc[m][dt][r] * linv);
        }
    }
}

// ---------------------------------------------------------------------------
extern "C" void kernel_launch(void* const* d_in, const int* in_sizes, int n_in,
                              void* d_out, int out_size, void* d_ws, size_t ws_size,
                              hipStream_t stream)
{
    const void* X  = d_in[0];
    const void* Wq = d_in[3];
    const void* bq = d_in[4];
    const void* Wk = d_in[5];
    const void* bk = d_in[6];
    const void* Wv = d_in[7];
    const void* bv = d_in[8];
    const void* Wo = d_in[9];
    const void* bo = d_in[10];
    const unsigned* probe = (const unsigned*)d_in[3];

    u16* ws  = (u16*)d_ws;
    u16* Xc  = ws;                   // [4096][2048]
    u16* WT  = Xc  + 8388608;        // [2048][2048] WqT, later WoT
    u16* WkT = WT  + 4194304;        // [512][2048]
    u16* WvT = WkT + 1048576;        // [512][2048]
    u16* bqc = WvT + 1048576;        // 2048
    u16* bkc = bqc + 2048;           // 512
    u16* bvc = bkc + 512;            // 512
    u16* boc = bvc + 512;            // 2048
    u16* Qb  = boc + 2048;           // [4096][2048]
    u16* Kb  = Qb  + 8388608;        // [4096][512]
    u16* Vb  = Kb  + 2097152;        // [4096][512]
    u16* VTb = Vb  + 2097152;        // [512][4096]
    u16* Ob  = VTb + 2097152;        // [4096][2048]

    convert_kernel<<<4096, 256, 0, stream>>>(X,  Xc,  8388608, probe);
    convert_kernel<<<1,    256, 0, stream>>>(bq, bqc, 2048, probe);
    convert_kernel<<<1,    256, 0, stream>>>(bk, bkc, 512,  probe);
    convert_kernel<<<1,    256, 0, stream>>>(bv, bvc, 512,  probe);
    convert_kernel<<<1,    256, 0, stream>>>(bo, boc, 2048, probe);

    tconv_kernel<<<dim3(16, 64), 256, 0, stream>>>(Wk, WkT, 2048, 512, probe);
    tconv_kernel<<<dim3(16, 64), 256, 0, stream>>>(Wv, WvT, 2048, 512, probe);
    tconv_kernel<<<dim3(64, 64), 256, 0, stream>>>(Wq, WT,  2048, 2048, probe);

    // log2(e)/sqrt(DH) folded into Q projection: exp() becomes exp2()
    gemm_bias_kernel<<<dim3(32, 16), 256, 0, stream>>>(Xc, WT,  bqc, Qb, 4096, 2048, 2048, nullptr, 0.12751743482175434f);
    gemm_bias_kernel<<<dim3(32, 4),  256, 0, stream>>>(Xc, WkT, bkc, Kb, 4096, 512, 2048, nullptr, 1.0f);
    gemm_bias_kernel<<<dim3(32, 4),  256, 0, stream>>>(Xc, WvT, bvc, Vb, 4096, 512, 2048, nullptr, 1.0f);

    transpose_kernel<<<dim3(16, 128), 256, 0, stream>>>(Vb, VTb, 4096, 512);

    flash_kernel<<<dim3(16, 16, 2), 256, 0, stream>>>(Qb, Kb, VTb, Ob);

    tconv_kernel<<<dim3(64, 64), 256, 0, stream>>>(Wo, WT, 2048, 2048, probe);

    gemm_bias_kernel<<<dim3(32, 16), 256, 0, stream>>>(Ob, WT, boc, d_out, 4096, 2048, 2048, probe, 1.0f);
}